// Round 13
// baseline (444.016 us; speedup 1.0000x reference)
//
#include <hip/hip_runtime.h>
#include <math.h>

#define HIDDEN 128
#define MAXBUK 512
#define E1_TPB 256
#define E1_EPT 4
#define E1_EPB (E1_TPB * E1_EPT)   // 1024 edges per block
#define E1_PPB (E1_EPB * 2)        // 2048 pairs per block

// W1 LDS layout v13: [hh 2][h' 64][kq 4][20]  (16 used + 4 pad, 16B-aligned)
//  kq stride 20 floats -> banks {0,20,8,28}: disjoint b128 spans; hh stride
//  5120 ≡ 0 mod 32 -> 2-way alias with hh partner (2-way is free, m136).
#define WKQ_STRIDE 20
#define WH_STRIDE  80          // 4 * 20
#define WHH_STRIDE 5120        // 64 * 80
#define W1S_FLOATS 10240       // 2 * 5120 = 40960 B

// ---- DPP cross-lane helpers (VALU pipe) ------------------------------------
__device__ __forceinline__ float dpp_xor1(float v) {
    int t = __builtin_amdgcn_update_dpp(0, __float_as_int(v),
                                        0xB1, 0xF, 0xF, true); // [1,0,3,2]
    return __int_as_float(t);
}
__device__ __forceinline__ float dpp_xor2(float v) {
    int t = __builtin_amdgcn_update_dpp(0, __float_as_int(v),
                                        0x4E, 0xF, 0xF, true); // [2,3,0,1]
    return __int_as_float(t);
}
__device__ __forceinline__ float quad_sum(float v) {   // sum over lane&3
    float a = v + dpp_xor1(v);
    return a + dpp_xor2(a);
}
// lane^4 exchange+add: row_half_mirror (i -> 7-i in 8-lane half) then
// quad_perm[3,2,1,0] (i^3) composes to i^4. Verified correct in v10 run.
__device__ __forceinline__ float xor4_add(float v) {
    int t1 = __builtin_amdgcn_update_dpp(0, __float_as_int(v),
                                         0x141, 0xF, 0xF, true); // half_mirror
    int t2 = __builtin_amdgcn_update_dpp(0, t1,
                                         0x1B, 0xF, 0xF, true);  // [3,2,1,0]
    return v + __int_as_float(t2);
}

// fast gelu: 0.5x(1+erf(x/sqrt2)), A&S 7.1.26, |erf err|<=2e-7
__device__ __forceinline__ float gelu_fast(float x) {
    const float u  = x * 0.70710678118654752f;
    const float au = fabsf(u);
    const float t  = __builtin_amdgcn_rcpf(fmaf(0.3275911f, au, 1.0f));
    float poly = fmaf(1.061405429f, t, -1.453152027f);
    poly = fmaf(poly, t, 1.421413741f);
    poly = fmaf(poly, t, -0.284496736f);
    poly = fmaf(poly, t, 0.254829592f);
    poly *= t;
    const float e = __expf(-au * au);
    const float erfabs = fmaf(-poly, e, 1.0f);
    const float erfv = copysignf(erfabs, u);
    return 0.5f * x * (1.0f + erfv);
}

// ---------------------------------------------------------------------------
// Pack: packed[n] = (h0,h1,<c0>,<c1>); netT[n] = (rain0,rain1);
// block 0 zeros the bucket counters.
// ---------------------------------------------------------------------------
__global__ __launch_bounds__(256) void pack_kernel(
    const float* __restrict__ h, const float* __restrict__ rain,
    float* __restrict__ packed, float* __restrict__ netT,
    unsigned* __restrict__ counters, int N)
{
    const int tid = threadIdx.x;
    const int b = blockIdx.x;
    if (b == 0)
        for (int i = tid; i < MAXBUK; i += 256) counters[i] = 0u;
    const int n = b * blockDim.x + tid;
    if (n >= N) return;
    *reinterpret_cast<float2*>(&packed[4 * n]) = make_float2(h[n], h[N + n]);
    *reinterpret_cast<float2*>(&netT[2 * n])   = make_float2(rain[n], rain[N + n]);
}

// ---------------------------------------------------------------------------
// Node kernel v13: 8-lane group = (hh 2) x (kq 4) owns 4 rows.
//  - 2R threads -> ~3 waves/SIMD (v12 was 1.5: dependency-stall-bound)
//  - each W b128 read reused for 4 rows (W LDS traffic stays 0.8 GB)
//  - acc[4][16] = 64 VGPRs, proven resident (v11/v12)
//  - hh halves joined via DPP xor4; gelu dedup by cndmask row-select
//    (static acc indices only); cf quad-summed over kq
// ---------------------------------------------------------------------------
__global__ __launch_bounds__(256, 3) void node_kernel(
    const float* __restrict__ z,     // [R][128]
    const float* __restrict__ W1,    // [128][64] row-major
    const float* __restrict__ b1, const float* __restrict__ W2,
    const float* __restrict__ b2, const float* __restrict__ Wa,
    const float* __restrict__ ba,
    float* __restrict__ packed, float* __restrict__ areas,
    int N, int R)
{
    __shared__ float w1s[W1S_FLOATS];   // 40960 B
    __shared__ float b1s[64], w2s[64], was[128];

    const int tid = threadIdx.x;
    for (int i = tid; i < 128 * 64; i += 256) {
        const int hrow = i >> 6, k = i & 63;
        const int hhs = hrow >> 6, hp = hrow & 63;
        const int kqs = k >> 4,  c = k & 15;
        w1s[hhs * WHH_STRIDE + hp * WH_STRIDE + kqs * WKQ_STRIDE + c] = W1[i];
    }
    if (tid < 64)       b1s[tid] = b1[tid];
    else if (tid < 128) w2s[tid - 64] = W2[tid - 64];
    else                was[tid - 128] = Wa[tid - 128];
    __syncthreads();

    const int l  = tid & 7;
    const int kq = l & 3;                            // k-quarter (16 k's)
    const int hh = l >> 2;                           // h-half (64 h's)
    const int r0 = ((blockIdx.x * 256 + tid) >> 3) * 4;  // group's 4 rows
    if (r0 >= R) return;                             // uniform per 8-group

    float acc[4][16];
#pragma unroll
    for (int r = 0; r < 4; ++r)
#pragma unroll
        for (int k = 0; k < 16; ++k) acc[r][k] = 0.f;
    float ad0 = 0.f, ad1 = 0.f, ad2 = 0.f, ad3 = 0.f;

    const size_t hoff = (size_t)hh * 64;
    const float* __restrict__ z0 = z + (size_t)(r0 + 0) * HIDDEN + hoff;
    const float* __restrict__ z1 = z + (size_t)(r0 + 1) * HIDDEN + hoff;
    const float* __restrict__ z2 = z + (size_t)(r0 + 2) * HIDDEN + hoff;
    const float* __restrict__ z3 = z + (size_t)(r0 + 3) * HIDDEN + hoff;
    const float* __restrict__ wbase =
        &w1s[hh * WHH_STRIDE + kq * WKQ_STRIDE];
    const float* __restrict__ wasl = &was[hh * 64];

#pragma unroll 2
    for (int i = 0; i < 16; ++i) {                   // h' in steps of 4
        const float4 zv0 = *reinterpret_cast<const float4*>(z0 + 4 * i);
        const float4 zv1 = *reinterpret_cast<const float4*>(z1 + 4 * i);
        const float4 zv2 = *reinterpret_cast<const float4*>(z2 + 4 * i);
        const float4 zv3 = *reinterpret_cast<const float4*>(z3 + 4 * i);
#pragma unroll
        for (int j = 0; j < 4; ++j) {
            const float a0 = (j == 0) ? zv0.x : (j == 1) ? zv0.y
                           : (j == 2) ? zv0.z : zv0.w;
            const float a1 = (j == 0) ? zv1.x : (j == 1) ? zv1.y
                           : (j == 2) ? zv1.z : zv1.w;
            const float a2 = (j == 0) ? zv2.x : (j == 1) ? zv2.y
                           : (j == 2) ? zv2.z : zv2.w;
            const float a3 = (j == 0) ? zv3.x : (j == 1) ? zv3.y
                           : (j == 2) ? zv3.z : zv3.w;
            const float* __restrict__ wrow = wbase + (4 * i + j) * WH_STRIDE;
#pragma unroll
            for (int kk = 0; kk < 4; ++kk) {
                const float4 w = *reinterpret_cast<const float4*>(wrow + 4 * kk);
                acc[0][4 * kk + 0] = fmaf(a0, w.x, acc[0][4 * kk + 0]);
                acc[1][4 * kk + 0] = fmaf(a1, w.x, acc[1][4 * kk + 0]);
                acc[2][4 * kk + 0] = fmaf(a2, w.x, acc[2][4 * kk + 0]);
                acc[3][4 * kk + 0] = fmaf(a3, w.x, acc[3][4 * kk + 0]);
                acc[0][4 * kk + 1] = fmaf(a0, w.y, acc[0][4 * kk + 1]);
                acc[1][4 * kk + 1] = fmaf(a1, w.y, acc[1][4 * kk + 1]);
                acc[2][4 * kk + 1] = fmaf(a2, w.y, acc[2][4 * kk + 1]);
                acc[3][4 * kk + 1] = fmaf(a3, w.y, acc[3][4 * kk + 1]);
                acc[0][4 * kk + 2] = fmaf(a0, w.z, acc[0][4 * kk + 2]);
                acc[1][4 * kk + 2] = fmaf(a1, w.z, acc[1][4 * kk + 2]);
                acc[2][4 * kk + 2] = fmaf(a2, w.z, acc[2][4 * kk + 2]);
                acc[3][4 * kk + 2] = fmaf(a3, w.z, acc[3][4 * kk + 2]);
                acc[0][4 * kk + 3] = fmaf(a0, w.w, acc[0][4 * kk + 3]);
                acc[1][4 * kk + 3] = fmaf(a1, w.w, acc[1][4 * kk + 3]);
                acc[2][4 * kk + 3] = fmaf(a2, w.w, acc[2][4 * kk + 3]);
                acc[3][4 * kk + 3] = fmaf(a3, w.w, acc[3][4 * kk + 3]);
            }
        }
        const float4 wa = *reinterpret_cast<const float4*>(&wasl[4 * i]);
        ad0 = fmaf(zv0.x, wa.x, ad0); ad0 = fmaf(zv0.y, wa.y, ad0);
        ad0 = fmaf(zv0.z, wa.z, ad0); ad0 = fmaf(zv0.w, wa.w, ad0);
        ad1 = fmaf(zv1.x, wa.x, ad1); ad1 = fmaf(zv1.y, wa.y, ad1);
        ad1 = fmaf(zv1.z, wa.z, ad1); ad1 = fmaf(zv1.w, wa.w, ad1);
        ad2 = fmaf(zv2.x, wa.x, ad2); ad2 = fmaf(zv2.y, wa.y, ad2);
        ad2 = fmaf(zv2.z, wa.z, ad2); ad2 = fmaf(zv2.w, wa.w, ad2);
        ad3 = fmaf(zv3.x, wa.x, ad3); ad3 = fmaf(zv3.y, wa.y, ad3);
        ad3 = fmaf(zv3.z, wa.z, ad3); ad3 = fmaf(zv3.w, wa.w, ad3);
    }

    // ---- epilogue ----
    // 1) join h-halves: acc and ad become full 128-h sums on both hh lanes
#pragma unroll
    for (int r = 0; r < 4; ++r)
#pragma unroll
        for (int k = 0; k < 16; ++k) acc[r][k] = xor4_add(acc[r][k]);
    ad0 = xor4_add(ad0); ad1 = xor4_add(ad1);
    ad2 = xor4_add(ad2); ad3 = xor4_add(ad3);

    // 2) gelu + W2 partial dot for THIS lane's 2 rows (2*hh, 2*hh+1),
    //    selected via cndmask (static acc indices, no scratch)
    const bool h1 = (hh != 0);
    float cfA = 0.f, cfB = 0.f;
#pragma unroll
    for (int k = 0; k < 16; ++k) {
        const float xA = (h1 ? acc[2][k] : acc[0][k]) + b1s[kq * 16 + k];
        const float xB = (h1 ? acc[3][k] : acc[1][k]) + b1s[kq * 16 + k];
        const float w2v = w2s[kq * 16 + k];
        cfA = fmaf(gelu_fast(xA), w2v, cfA);
        cfB = fmaf(gelu_fast(xB), w2v, cfB);
    }
    // 3) sum the 4 k-quarters (quad = lanes with same hh)
    cfA = quad_sum(cfA);
    cfB = quad_sum(cfB);

    // 4) lane (kq<2) writes row r0 + 2*hh + kq
    if (kq < 2) {
        const int row = r0 + 2 * hh + kq;
        const float cfv = (kq == 0) ? cfA : cfB;
        const float adv0 = (kq == 0) ? (h1 ? ad2 : ad0)
                                     : (h1 ? ad3 : ad1);
        const float cv   = 1.0f / (1.0f + expf(-(cfv + b2[0])));
        const float adv  = adv0 + ba[0];
        const float area = fmaxf(adv, 0.f) + log1pf(expf(-fabsf(adv)));
        const int bb = (row >= N) ? 1 : 0;
        const int n = row - bb * N;
        packed[4 * n + 2 + bb] = cv;
        areas[row] = area;
    }
}

// ---------------------------------------------------------------------------
// E1: per-edge flows + in-block counting-sort of (node, +/-f0,f1) pairs into
// per-bucket global segments (bucket = node>>8). ~196 int atomics per block.
// ---------------------------------------------------------------------------
__global__ __launch_bounds__(E1_TPB) void edge_bin_kernel(
    const int* __restrict__ eidx,      // [2][E]
    const float* __restrict__ packed,  // [N][4] = h0,h1,c0,c1
    float* __restrict__ flows,         // [2][E]
    unsigned* __restrict__ keysG,      // [nbuk][cap]
    float2* __restrict__ valsG,        // [nbuk][cap]
    unsigned* __restrict__ counters,   // [nbuk]
    int E, int nbuk, int cap)
{
    __shared__ unsigned hist[MAXBUK];
    __shared__ unsigned base[MAXBUK];
    __shared__ unsigned gbase[MAXBUK];
    __shared__ unsigned scan[E1_TPB];
    __shared__ unsigned skey[E1_PPB];
    __shared__ float2   sval[E1_PPB];

    const int tid = threadIdx.x;
    const int e0  = blockIdx.x * E1_EPB;

    for (int i = tid; i < nbuk; i += E1_TPB) hist[i] = 0;
    __syncthreads();

    unsigned mykey[2 * E1_EPT];
    unsigned myoff[2 * E1_EPT];
    float2   myval[2 * E1_EPT];

#pragma unroll
    for (int j = 0; j < E1_EPT; ++j) {
        const int e = e0 + j * E1_TPB + tid;
        unsigned kd = 0xFFFFFFFFu, ks = 0xFFFFFFFFu;
        float2 vd = make_float2(0.f, 0.f), vs = vd;
        if (e < E) {
            const int s = eidx[e];
            const int d = eidx[E + e];
            const float4 ps = *reinterpret_cast<const float4*>(&packed[4 * s]);
            const float4 pd = *reinterpret_cast<const float4*>(&packed[4 * d]);

            float dh = ps.x - pd.x;
            float sg = (dh > 0.f) ? 1.f : ((dh < 0.f) ? -1.f : 0.f);
            float f0 = ps.z * sg * sqrtf(fabsf(dh) + 1e-6f);
            f0 = fminf(fmaxf(f0, -10.0f), 10.0f);

            dh = ps.y - pd.y;
            sg = (dh > 0.f) ? 1.f : ((dh < 0.f) ? -1.f : 0.f);
            float f1 = ps.w * sg * sqrtf(fabsf(dh) + 1e-6f);
            f1 = fminf(fmaxf(f1, -10.0f), 10.0f);

            flows[e] = f0;
            flows[(size_t)E + e] = f1;

            kd = (unsigned)d; vd = make_float2(f0, f1);
            ks = (unsigned)s; vs = make_float2(-f0, -f1);
        }
        mykey[2 * j]     = kd; myval[2 * j]     = vd;
        mykey[2 * j + 1] = ks; myval[2 * j + 1] = vs;
        if (kd != 0xFFFFFFFFu) {
            myoff[2 * j]     = atomicAdd(&hist[kd >> 8], 1u);
            myoff[2 * j + 1] = atomicAdd(&hist[ks >> 8], 1u);
        }
    }
    __syncthreads();

    // Hillis-Steele inclusive scan of hist (nbuk <= 256)
    const unsigned hv = (tid < nbuk) ? hist[tid] : 0u;
    scan[tid] = hv;
    __syncthreads();
    for (int off = 1; off < E1_TPB; off <<= 1) {
        unsigned t = (tid >= off) ? scan[tid - off] : 0u;
        __syncthreads();
        scan[tid] += t;
        __syncthreads();
    }
    if (tid < nbuk) {
        base[tid] = scan[tid] - hv;
        if (hv > 0) gbase[tid] = atomicAdd(&counters[tid], hv);
    }
    __syncthreads();

#pragma unroll
    for (int j = 0; j < 2 * E1_EPT; ++j) {
        const unsigned k = mykey[j];
        if (k != 0xFFFFFFFFu) {
            const unsigned idx = base[k >> 8] + myoff[j];
            skey[idx] = k;
            sval[idx] = myval[j];
        }
    }
    __syncthreads();

    const int tot = 2 * min(E1_EPB, E - e0);
    for (int i = tid; i < tot; i += E1_TPB) {
        const unsigned k = skey[i];
        const unsigned bb = k >> 8;
        const unsigned pos = gbase[bb] + ((unsigned)i - base[bb]);
        if (pos < (unsigned)cap) {
            keysG[(size_t)bb * cap + pos] = k;
            valsG[(size_t)bb * cap + pos] = sval[i];
        }
    }
}

// ---------------------------------------------------------------------------
// E2: one block (512 thr) per bucket; FOUR LDS accumulator copies cut
// same-node atomic serialization. Fused h-update. No global f32 atomics.
// ---------------------------------------------------------------------------
__global__ __launch_bounds__(512) void bucket_reduce_kernel(
    const unsigned* __restrict__ keysG, const float2* __restrict__ valsG,
    const unsigned* __restrict__ counters,
    const float* __restrict__ h, const float* __restrict__ rain,
    const float* __restrict__ areas,
    float* __restrict__ hnew, int N, int cap)
{
    __shared__ float accx[4][256], accy[4][256];   // 8 KB
    const int tid = threadIdx.x;
    const int b = blockIdx.x;
    const int q = tid >> 7;                        // 4 groups of 128
    {
        float* fx = &accx[0][0];
        float* fy = &accy[0][0];
        fx[tid] = 0.f; fx[tid + 512] = 0.f;
        fy[tid] = 0.f; fy[tid + 512] = 0.f;
    }
    __syncthreads();

    const int cnt = min((int)counters[b], cap);
    const unsigned* __restrict__ sk = keysG + (size_t)b * cap;
    const float2*  __restrict__  sv = valsG + (size_t)b * cap;
    for (int i = tid; i < cnt; i += 512) {
        const unsigned k = sk[i];
        const float2 v2 = sv[i];
        const int loc = (int)(k & 255u);
        atomicAdd(&accx[q][loc], v2.x);
        atomicAdd(&accy[q][loc], v2.y);
    }
    __syncthreads();

    if (tid < 256) {
        const int n = (b << 8) + tid;
        if (n < N) {
            const float net0 = rain[n]     + ((accx[0][tid] + accx[1][tid])
                                           + (accx[2][tid] + accx[3][tid]));
            const float net1 = rain[N + n] + ((accy[0][tid] + accy[1][tid])
                                           + (accy[2][tid] + accy[3][tid]));
            float dh0 = 300.0f * net0 / (areas[n] + 1e-6f);
            dh0 = fminf(fmaxf(dh0, -1.0f), 1.0f);
            hnew[n] = h[n] + dh0;
            float dh1 = 300.0f * net1 / (areas[N + n] + 1e-6f);
            dh1 = fminf(fmaxf(dh1, -1.0f), 1.0f);
            hnew[N + n] = h[N + n] + dh1;
        }
    }
}

// ---------------------------------------------------------------------------
// Fallback path (ws too small): atomic edge + update kernels.
// ---------------------------------------------------------------------------
__global__ __launch_bounds__(256) void edge_kernel(
    const int* __restrict__ eidx, const float* __restrict__ packed,
    float* __restrict__ flows, float* __restrict__ netT, int E)
{
    const int e = blockIdx.x * blockDim.x + threadIdx.x;
    if (e >= E) return;
    const int s = eidx[e];
    const int d = eidx[E + e];
    const float4 ps = *reinterpret_cast<const float4*>(&packed[4 * s]);
    const float4 pd = *reinterpret_cast<const float4*>(&packed[4 * d]);
    {
        const float dh = ps.x - pd.x;
        const float sg = (dh > 0.f) ? 1.f : ((dh < 0.f) ? -1.f : 0.f);
        float f = ps.z * sg * sqrtf(fabsf(dh) + 1e-6f);
        f = fminf(fmaxf(f, -10.0f), 10.0f);
        flows[e] = f;
        unsafeAtomicAdd(&netT[2 * d + 0],  f);
        unsafeAtomicAdd(&netT[2 * s + 0], -f);
    }
    {
        const float dh = ps.y - pd.y;
        const float sg = (dh > 0.f) ? 1.f : ((dh < 0.f) ? -1.f : 0.f);
        float f = ps.w * sg * sqrtf(fabsf(dh) + 1e-6f);
        f = fminf(fmaxf(f, -10.0f), 10.0f);
        flows[(size_t)E + e] = f;
        unsafeAtomicAdd(&netT[2 * d + 1],  f);
        unsafeAtomicAdd(&netT[2 * s + 1], -f);
    }
}

__global__ __launch_bounds__(256) void update_kernel(
    const float* __restrict__ h, const float* __restrict__ netT,
    const float* __restrict__ areas, float* __restrict__ hnew, int N)
{
    const int n = blockIdx.x * blockDim.x + threadIdx.x;
    if (n >= N) return;
    const float2 nv = *reinterpret_cast<const float2*>(&netT[2 * n]);
    float dh0 = 300.0f * nv.x / (areas[n] + 1e-6f);
    dh0 = fminf(fmaxf(dh0, -1.0f), 1.0f);
    hnew[n] = h[n] + dh0;
    float dh1 = 300.0f * nv.y / (areas[N + n] + 1e-6f);
    dh1 = fminf(fmaxf(dh1, -1.0f), 1.0f);
    hnew[N + n] = h[N + n] + dh1;
}

extern "C" void kernel_launch(void* const* d_in, const int* in_sizes, int n_in,
                              void* d_out, int out_size, void* d_ws, size_t ws_size,
                              hipStream_t stream)
{
    const float* h    = (const float*)d_in[0];
    const float* z    = (const float*)d_in[1];
    const int*   eidx = (const int*)  d_in[2];
    const float* rain = (const float*)d_in[4];
    const float* W1   = (const float*)d_in[5];
    const float* b1   = (const float*)d_in[6];
    const float* W2   = (const float*)d_in[7];
    const float* b2   = (const float*)d_in[8];
    const float* Wa   = (const float*)d_in[9];
    const float* ba   = (const float*)d_in[10];

    const int R = in_sizes[0];      // B*N
    const int E = in_sizes[3];
    const int N = R / 2;

    float* out_h     = (float*)d_out;
    float* out_flows = out_h + R;

    char* wsB = (char*)d_ws;
    size_t off = 0;
    auto take = [&](size_t bytes) -> char* {
        char* p = wsB + off;
        off = (off + bytes + 255) & ~(size_t)255;
        return p;
    };
    float*    packed   = (float*)   take((size_t)4 * N * 4);
    float*    areas    = (float*)   take((size_t)R * 4);
    float*    netT     = (float*)   take((size_t)2 * N * 4);
    unsigned* counters = (unsigned*)take(MAXBUK * 4);

    const int nbuk = (N + 255) >> 8;
    int cap = (int)(((size_t)2 * E / (nbuk > 0 ? nbuk : 1)) * 5 / 4 + 512);
    cap = (cap + 255) & ~255;
    unsigned* keysG = (unsigned*)take((size_t)nbuk * cap * 4);
    float2*   valsG = (float2*)  take((size_t)nbuk * cap * 8);
    const bool binned = (off <= ws_size) && (nbuk <= 256);

    pack_kernel<<<(N + 255) / 256, 256, 0, stream>>>(h, rain, packed, netT,
                                                     counters, N);
    // 2R threads: 8-lane groups (2 hh x 4 kq) per 4 rows
    node_kernel<<<(2 * R + 255) / 256, 256, 0, stream>>>(z, W1, b1, W2, b2,
                                                         Wa, ba, packed,
                                                         areas, N, R);
    if (binned) {
        edge_bin_kernel<<<(E + E1_EPB - 1) / E1_EPB, E1_TPB, 0, stream>>>(
            eidx, packed, out_flows, keysG, valsG, counters, E, nbuk, cap);
        bucket_reduce_kernel<<<nbuk, 512, 0, stream>>>(
            keysG, valsG, counters, h, rain, areas, out_h, N, cap);
    } else {
        edge_kernel<<<(E + 255) / 256, 256, 0, stream>>>(eidx, packed,
                                                         out_flows, netT, E);
        update_kernel<<<(N + 255) / 256, 256, 0, stream>>>(h, netT, areas,
                                                           out_h, N);
    }
}

// Round 14
// 102.471 us; speedup vs baseline: 4.3331x; 4.3331x over previous
//
#include <hip/hip_runtime.h>
#include <math.h>

#define HIDDEN 128
#define MAXBUK 512
#define E1_TPB 256
#define E1_EPT 4
#define E1_EPB (E1_TPB * E1_EPT)   // 1024 edges per block
#define E1_PPB (E1_EPB * 2)        // 2048 pairs per block

// W1 LDS layout: [h 0..128)][68]  (64 cols used + 4 pad)
#define W1S_H_STRIDE 68

// ---- DPP cross-lane helpers (VALU pipe) ------------------------------------
__device__ __forceinline__ float dpp_xor1(float v) {
    int t = __builtin_amdgcn_update_dpp(0, __float_as_int(v),
                                        0xB1, 0xF, 0xF, true); // [1,0,3,2]
    return __int_as_float(t);
}
__device__ __forceinline__ float dpp_xor2(float v) {
    int t = __builtin_amdgcn_update_dpp(0, __float_as_int(v),
                                        0x4E, 0xF, 0xF, true); // [2,3,0,1]
    return __int_as_float(t);
}
__device__ __forceinline__ float quad_sum(float v) {   // sum over lane&3
    float a = v + dpp_xor1(v);
    return a + dpp_xor2(a);
}
// lane^4 exchange+add (within aligned 8-lane group): half_mirror (i^7) then
// quad_perm[3,2,1,0] (i^3) composes to i^4. Correctness verified in v10/v13.
__device__ __forceinline__ float xor4_add(float v) {
    int t1 = __builtin_amdgcn_update_dpp(0, __float_as_int(v),
                                         0x141, 0xF, 0xF, true); // half_mirror
    int t2 = __builtin_amdgcn_update_dpp(0, t1,
                                         0x1B, 0xF, 0xF, true);  // [3,2,1,0]
    return v + __int_as_float(t2);
}
__device__ __forceinline__ float sum8(float v) {       // sum over lane&7
    return xor4_add(quad_sum(v));
}

// fast gelu: 0.5x(1+erf(x/sqrt2)), A&S 7.1.26, |erf err|<=2e-7
__device__ __forceinline__ float gelu_fast(float x) {
    const float u  = x * 0.70710678118654752f;
    const float au = fabsf(u);
    const float t  = __builtin_amdgcn_rcpf(fmaf(0.3275911f, au, 1.0f));
    float poly = fmaf(1.061405429f, t, -1.453152027f);
    poly = fmaf(poly, t, 1.421413741f);
    poly = fmaf(poly, t, -0.284496736f);
    poly = fmaf(poly, t, 0.254829592f);
    poly *= t;
    const float e = __expf(-au * au);
    const float erfabs = fmaf(-poly, e, 1.0f);
    const float erfv = copysignf(erfabs, u);
    return 0.5f * x * (1.0f + erfv);
}

// ---------------------------------------------------------------------------
// Pack: packed[n] = (h0,h1,<c0>,<c1>); netT[n] = (rain0,rain1);
// block 0 zeros the bucket counters.
// ---------------------------------------------------------------------------
__global__ __launch_bounds__(256) void pack_kernel(
    const float* __restrict__ h, const float* __restrict__ rain,
    float* __restrict__ packed, float* __restrict__ netT,
    unsigned* __restrict__ counters, int N)
{
    const int tid = threadIdx.x;
    const int b = blockIdx.x;
    if (b == 0)
        for (int i = tid; i < MAXBUK; i += 256) counters[i] = 0u;
    const int n = b * blockDim.x + tid;
    if (n >= N) return;
    *reinterpret_cast<float2*>(&packed[4 * n]) = make_float2(h[n], h[N + n]);
    *reinterpret_cast<float2*>(&netT[2 * n])   = make_float2(rain[n], rain[N + n]);
}

// ---------------------------------------------------------------------------
// Node kernel v14: 8-lane group = 8 k-eighths own 4 rows.
//  - 2R threads -> ~3 waves/SIMD (v12's 1.5 was dependency-stall-bound)
//  - acc[4][8] = 32 VGPRs only; NO cross-lane ops on acc (v13's spill cause)
//  - each W b128 LDS read serves 4 rows -> W traffic 0.82 GB (as v12)
//  - z streamed float4 with 1-step register prefetch (zc/zn)
//  - only the scalar cf dot is cross-lane reduced (sum8, 3 DPP)
// ---------------------------------------------------------------------------
__global__ __launch_bounds__(256) void node_kernel(
    const float* __restrict__ z,     // [R][128]
    const float* __restrict__ W1,    // [128][64] row-major
    const float* __restrict__ b1, const float* __restrict__ W2,
    const float* __restrict__ b2, const float* __restrict__ Wa,
    const float* __restrict__ ba,
    float* __restrict__ packed, float* __restrict__ areas,
    int N, int R)
{
    __shared__ float w1s[128 * W1S_H_STRIDE];   // 34816 B
    __shared__ float b1s[64], w2s[64], was[128];

    const int tid = threadIdx.x;
    for (int i = tid; i < 128 * 64; i += 256) {
        const int hh = i >> 6, k = i & 63;
        w1s[hh * W1S_H_STRIDE + k] = W1[i];
    }
    if (tid < 64)       b1s[tid] = b1[tid];
    else if (tid < 128) w2s[tid - 64] = W2[tid - 64];
    else                was[tid - 128] = Wa[tid - 128];
    __syncthreads();

    const int kq = tid & 7;                          // k-eighth (8 k's)
    const int r0 = ((blockIdx.x * 256 + tid) >> 3) * 4;  // group's 4 rows
    if (r0 >= R) return;                             // R % 4 == 0

    float acc[4][8];
#pragma unroll
    for (int r = 0; r < 4; ++r)
#pragma unroll
        for (int k = 0; k < 8; ++k) acc[r][k] = 0.f;
    float ad0 = 0.f, ad1 = 0.f, ad2 = 0.f, ad3 = 0.f;

    const float* __restrict__ z0 = z + (size_t)(r0 + 0) * HIDDEN;
    const float* __restrict__ z1 = z + (size_t)(r0 + 1) * HIDDEN;
    const float* __restrict__ z2 = z + (size_t)(r0 + 2) * HIDDEN;
    const float* __restrict__ z3 = z + (size_t)(r0 + 3) * HIDDEN;
    const float* __restrict__ wq = &w1s[kq * 8];

    // prefetch i=0
    float4 zc0 = *reinterpret_cast<const float4*>(z0);
    float4 zc1 = *reinterpret_cast<const float4*>(z1);
    float4 zc2 = *reinterpret_cast<const float4*>(z2);
    float4 zc3 = *reinterpret_cast<const float4*>(z3);

    for (int i = 0; i < 32; ++i) {                   // 4 h's per step
        float4 zn0, zn1, zn2, zn3;
        if (i < 31) {
            zn0 = *reinterpret_cast<const float4*>(z0 + 4 * i + 4);
            zn1 = *reinterpret_cast<const float4*>(z1 + 4 * i + 4);
            zn2 = *reinterpret_cast<const float4*>(z2 + 4 * i + 4);
            zn3 = *reinterpret_cast<const float4*>(z3 + 4 * i + 4);
        }
#pragma unroll
        for (int j = 0; j < 4; ++j) {
            const float a0 = (j == 0) ? zc0.x : (j == 1) ? zc0.y
                           : (j == 2) ? zc0.z : zc0.w;
            const float a1 = (j == 0) ? zc1.x : (j == 1) ? zc1.y
                           : (j == 2) ? zc1.z : zc1.w;
            const float a2 = (j == 0) ? zc2.x : (j == 1) ? zc2.y
                           : (j == 2) ? zc2.z : zc2.w;
            const float a3 = (j == 0) ? zc3.x : (j == 1) ? zc3.y
                           : (j == 2) ? zc3.z : zc3.w;
            const float* __restrict__ wrow = wq + (4 * i + j) * W1S_H_STRIDE;
            const float4 w0 = *reinterpret_cast<const float4*>(wrow);
            const float4 w1v = *reinterpret_cast<const float4*>(wrow + 4);
            acc[0][0] = fmaf(a0, w0.x, acc[0][0]);
            acc[1][0] = fmaf(a1, w0.x, acc[1][0]);
            acc[2][0] = fmaf(a2, w0.x, acc[2][0]);
            acc[3][0] = fmaf(a3, w0.x, acc[3][0]);
            acc[0][1] = fmaf(a0, w0.y, acc[0][1]);
            acc[1][1] = fmaf(a1, w0.y, acc[1][1]);
            acc[2][1] = fmaf(a2, w0.y, acc[2][1]);
            acc[3][1] = fmaf(a3, w0.y, acc[3][1]);
            acc[0][2] = fmaf(a0, w0.z, acc[0][2]);
            acc[1][2] = fmaf(a1, w0.z, acc[1][2]);
            acc[2][2] = fmaf(a2, w0.z, acc[2][2]);
            acc[3][2] = fmaf(a3, w0.z, acc[3][2]);
            acc[0][3] = fmaf(a0, w0.w, acc[0][3]);
            acc[1][3] = fmaf(a1, w0.w, acc[1][3]);
            acc[2][3] = fmaf(a2, w0.w, acc[2][3]);
            acc[3][3] = fmaf(a3, w0.w, acc[3][3]);
            acc[0][4] = fmaf(a0, w1v.x, acc[0][4]);
            acc[1][4] = fmaf(a1, w1v.x, acc[1][4]);
            acc[2][4] = fmaf(a2, w1v.x, acc[2][4]);
            acc[3][4] = fmaf(a3, w1v.x, acc[3][4]);
            acc[0][5] = fmaf(a0, w1v.y, acc[0][5]);
            acc[1][5] = fmaf(a1, w1v.y, acc[1][5]);
            acc[2][5] = fmaf(a2, w1v.y, acc[2][5]);
            acc[3][5] = fmaf(a3, w1v.y, acc[3][5]);
            acc[0][6] = fmaf(a0, w1v.z, acc[0][6]);
            acc[1][6] = fmaf(a1, w1v.z, acc[1][6]);
            acc[2][6] = fmaf(a2, w1v.z, acc[2][6]);
            acc[3][6] = fmaf(a3, w1v.z, acc[3][6]);
            acc[0][7] = fmaf(a0, w1v.w, acc[0][7]);
            acc[1][7] = fmaf(a1, w1v.w, acc[1][7]);
            acc[2][7] = fmaf(a2, w1v.w, acc[2][7]);
            acc[3][7] = fmaf(a3, w1v.w, acc[3][7]);
        }
        const float4 wa = *reinterpret_cast<const float4*>(&was[4 * i]);
        ad0 = fmaf(zc0.x, wa.x, ad0); ad0 = fmaf(zc0.y, wa.y, ad0);
        ad0 = fmaf(zc0.z, wa.z, ad0); ad0 = fmaf(zc0.w, wa.w, ad0);
        ad1 = fmaf(zc1.x, wa.x, ad1); ad1 = fmaf(zc1.y, wa.y, ad1);
        ad1 = fmaf(zc1.z, wa.z, ad1); ad1 = fmaf(zc1.w, wa.w, ad1);
        ad2 = fmaf(zc2.x, wa.x, ad2); ad2 = fmaf(zc2.y, wa.y, ad2);
        ad2 = fmaf(zc2.z, wa.z, ad2); ad2 = fmaf(zc2.w, wa.w, ad2);
        ad3 = fmaf(zc3.x, wa.x, ad3); ad3 = fmaf(zc3.y, wa.y, ad3);
        ad3 = fmaf(zc3.z, wa.z, ad3); ad3 = fmaf(zc3.w, wa.w, ad3);
        zc0 = zn0; zc1 = zn1; zc2 = zn2; zc3 = zn3;
    }

    // ---- epilogue: per row, gelu over this lane's 8 k's (acc dies here),
    //      then sum8 across the 8 lanes. No cross-lane ops on acc arrays.
    float cfq[4];
#pragma unroll
    for (int r = 0; r < 4; ++r) {
        float cf = 0.f;
#pragma unroll
        for (int k = 0; k < 8; ++k) {
            const float x = acc[r][k] + b1s[kq * 8 + k];
            cf = fmaf(gelu_fast(x), w2s[kq * 8 + k], cf);
        }
        cfq[r] = sum8(cf);              // full 64-k dot, same on all 8 lanes
    }

    // lane kq<4 writes row r0+kq (static cndmask selects, no dynamic index)
    if (kq < 4) {
        const int row = r0 + kq;
        const float cfv = (kq == 0) ? cfq[0] : (kq == 1) ? cfq[1]
                        : (kq == 2) ? cfq[2] : cfq[3];
        const float adp = (kq == 0) ? ad0 : (kq == 1) ? ad1
                        : (kq == 2) ? ad2 : ad3;
        const float cv   = 1.0f / (1.0f + expf(-(cfv + b2[0])));
        const float adv  = adp + ba[0];
        const float area = fmaxf(adv, 0.f) + log1pf(expf(-fabsf(adv)));
        const int bb = (row >= N) ? 1 : 0;
        const int n = row - bb * N;
        packed[4 * n + 2 + bb] = cv;
        areas[row] = area;
    }
}

// ---------------------------------------------------------------------------
// E1: per-edge flows + in-block counting-sort of (node, +/-f0,f1) pairs into
// per-bucket global segments (bucket = node>>8). ~196 int atomics per block.
// ---------------------------------------------------------------------------
__global__ __launch_bounds__(E1_TPB) void edge_bin_kernel(
    const int* __restrict__ eidx,      // [2][E]
    const float* __restrict__ packed,  // [N][4] = h0,h1,c0,c1
    float* __restrict__ flows,         // [2][E]
    unsigned* __restrict__ keysG,      // [nbuk][cap]
    float2* __restrict__ valsG,        // [nbuk][cap]
    unsigned* __restrict__ counters,   // [nbuk]
    int E, int nbuk, int cap)
{
    __shared__ unsigned hist[MAXBUK];
    __shared__ unsigned base[MAXBUK];
    __shared__ unsigned gbase[MAXBUK];
    __shared__ unsigned scan[E1_TPB];
    __shared__ unsigned skey[E1_PPB];
    __shared__ float2   sval[E1_PPB];

    const int tid = threadIdx.x;
    const int e0  = blockIdx.x * E1_EPB;

    for (int i = tid; i < nbuk; i += E1_TPB) hist[i] = 0;
    __syncthreads();

    unsigned mykey[2 * E1_EPT];
    unsigned myoff[2 * E1_EPT];
    float2   myval[2 * E1_EPT];

#pragma unroll
    for (int j = 0; j < E1_EPT; ++j) {
        const int e = e0 + j * E1_TPB + tid;
        unsigned kd = 0xFFFFFFFFu, ks = 0xFFFFFFFFu;
        float2 vd = make_float2(0.f, 0.f), vs = vd;
        if (e < E) {
            const int s = eidx[e];
            const int d = eidx[E + e];
            const float4 ps = *reinterpret_cast<const float4*>(&packed[4 * s]);
            const float4 pd = *reinterpret_cast<const float4*>(&packed[4 * d]);

            float dh = ps.x - pd.x;
            float sg = (dh > 0.f) ? 1.f : ((dh < 0.f) ? -1.f : 0.f);
            float f0 = ps.z * sg * sqrtf(fabsf(dh) + 1e-6f);
            f0 = fminf(fmaxf(f0, -10.0f), 10.0f);

            dh = ps.y - pd.y;
            sg = (dh > 0.f) ? 1.f : ((dh < 0.f) ? -1.f : 0.f);
            float f1 = ps.w * sg * sqrtf(fabsf(dh) + 1e-6f);
            f1 = fminf(fmaxf(f1, -10.0f), 10.0f);

            flows[e] = f0;
            flows[(size_t)E + e] = f1;

            kd = (unsigned)d; vd = make_float2(f0, f1);
            ks = (unsigned)s; vs = make_float2(-f0, -f1);
        }
        mykey[2 * j]     = kd; myval[2 * j]     = vd;
        mykey[2 * j + 1] = ks; myval[2 * j + 1] = vs;
        if (kd != 0xFFFFFFFFu) {
            myoff[2 * j]     = atomicAdd(&hist[kd >> 8], 1u);
            myoff[2 * j + 1] = atomicAdd(&hist[ks >> 8], 1u);
        }
    }
    __syncthreads();

    // Hillis-Steele inclusive scan of hist (nbuk <= 256)
    const unsigned hv = (tid < nbuk) ? hist[tid] : 0u;
    scan[tid] = hv;
    __syncthreads();
    for (int off = 1; off < E1_TPB; off <<= 1) {
        unsigned t = (tid >= off) ? scan[tid - off] : 0u;
        __syncthreads();
        scan[tid] += t;
        __syncthreads();
    }
    if (tid < nbuk) {
        base[tid] = scan[tid] - hv;
        if (hv > 0) gbase[tid] = atomicAdd(&counters[tid], hv);
    }
    __syncthreads();

#pragma unroll
    for (int j = 0; j < 2 * E1_EPT; ++j) {
        const unsigned k = mykey[j];
        if (k != 0xFFFFFFFFu) {
            const unsigned idx = base[k >> 8] + myoff[j];
            skey[idx] = k;
            sval[idx] = myval[j];
        }
    }
    __syncthreads();

    const int tot = 2 * min(E1_EPB, E - e0);
    for (int i = tid; i < tot; i += E1_TPB) {
        const unsigned k = skey[i];
        const unsigned bb = k >> 8;
        const unsigned pos = gbase[bb] + ((unsigned)i - base[bb]);
        if (pos < (unsigned)cap) {
            keysG[(size_t)bb * cap + pos] = k;
            valsG[(size_t)bb * cap + pos] = sval[i];
        }
    }
}

// ---------------------------------------------------------------------------
// E2: one block (512 thr) per bucket; FOUR LDS accumulator copies cut
// same-node atomic serialization. Fused h-update. No global f32 atomics.
// ---------------------------------------------------------------------------
__global__ __launch_bounds__(512) void bucket_reduce_kernel(
    const unsigned* __restrict__ keysG, const float2* __restrict__ valsG,
    const unsigned* __restrict__ counters,
    const float* __restrict__ h, const float* __restrict__ rain,
    const float* __restrict__ areas,
    float* __restrict__ hnew, int N, int cap)
{
    __shared__ float accx[4][256], accy[4][256];   // 8 KB
    const int tid = threadIdx.x;
    const int b = blockIdx.x;
    const int q = tid >> 7;                        // 4 groups of 128
    {
        float* fx = &accx[0][0];
        float* fy = &accy[0][0];
        fx[tid] = 0.f; fx[tid + 512] = 0.f;
        fy[tid] = 0.f; fy[tid + 512] = 0.f;
    }
    __syncthreads();

    const int cnt = min((int)counters[b], cap);
    const unsigned* __restrict__ sk = keysG + (size_t)b * cap;
    const float2*  __restrict__  sv = valsG + (size_t)b * cap;
    for (int i = tid; i < cnt; i += 512) {
        const unsigned k = sk[i];
        const float2 v2 = sv[i];
        const int loc = (int)(k & 255u);
        atomicAdd(&accx[q][loc], v2.x);
        atomicAdd(&accy[q][loc], v2.y);
    }
    __syncthreads();

    if (tid < 256) {
        const int n = (b << 8) + tid;
        if (n < N) {
            const float net0 = rain[n]     + ((accx[0][tid] + accx[1][tid])
                                           + (accx[2][tid] + accx[3][tid]));
            const float net1 = rain[N + n] + ((accy[0][tid] + accy[1][tid])
                                           + (accy[2][tid] + accy[3][tid]));
            float dh0 = 300.0f * net0 / (areas[n] + 1e-6f);
            dh0 = fminf(fmaxf(dh0, -1.0f), 1.0f);
            hnew[n] = h[n] + dh0;
            float dh1 = 300.0f * net1 / (areas[N + n] + 1e-6f);
            dh1 = fminf(fmaxf(dh1, -1.0f), 1.0f);
            hnew[N + n] = h[N + n] + dh1;
        }
    }
}

// ---------------------------------------------------------------------------
// Fallback path (ws too small): atomic edge + update kernels.
// ---------------------------------------------------------------------------
__global__ __launch_bounds__(256) void edge_kernel(
    const int* __restrict__ eidx, const float* __restrict__ packed,
    float* __restrict__ flows, float* __restrict__ netT, int E)
{
    const int e = blockIdx.x * blockDim.x + threadIdx.x;
    if (e >= E) return;
    const int s = eidx[e];
    const int d = eidx[E + e];
    const float4 ps = *reinterpret_cast<const float4*>(&packed[4 * s]);
    const float4 pd = *reinterpret_cast<const float4*>(&packed[4 * d]);
    {
        const float dh = ps.x - pd.x;
        const float sg = (dh > 0.f) ? 1.f : ((dh < 0.f) ? -1.f : 0.f);
        float f = ps.z * sg * sqrtf(fabsf(dh) + 1e-6f);
        f = fminf(fmaxf(f, -10.0f), 10.0f);
        flows[e] = f;
        unsafeAtomicAdd(&netT[2 * d + 0],  f);
        unsafeAtomicAdd(&netT[2 * s + 0], -f);
    }
    {
        const float dh = ps.y - pd.y;
        const float sg = (dh > 0.f) ? 1.f : ((dh < 0.f) ? -1.f : 0.f);
        float f = ps.w * sg * sqrtf(fabsf(dh) + 1e-6f);
        f = fminf(fmaxf(f, -10.0f), 10.0f);
        flows[(size_t)E + e] = f;
        unsafeAtomicAdd(&netT[2 * d + 1],  f);
        unsafeAtomicAdd(&netT[2 * s + 1], -f);
    }
}

__global__ __launch_bounds__(256) void update_kernel(
    const float* __restrict__ h, const float* __restrict__ netT,
    const float* __restrict__ areas, float* __restrict__ hnew, int N)
{
    const int n = blockIdx.x * blockDim.x + threadIdx.x;
    if (n >= N) return;
    const float2 nv = *reinterpret_cast<const float2*>(&netT[2 * n]);
    float dh0 = 300.0f * nv.x / (areas[n] + 1e-6f);
    dh0 = fminf(fmaxf(dh0, -1.0f), 1.0f);
    hnew[n] = h[n] + dh0;
    float dh1 = 300.0f * nv.y / (areas[N + n] + 1e-6f);
    dh1 = fminf(fmaxf(dh1, -1.0f), 1.0f);
    hnew[N + n] = h[N + n] + dh1;
}

extern "C" void kernel_launch(void* const* d_in, const int* in_sizes, int n_in,
                              void* d_out, int out_size, void* d_ws, size_t ws_size,
                              hipStream_t stream)
{
    const float* h    = (const float*)d_in[0];
    const float* z    = (const float*)d_in[1];
    const int*   eidx = (const int*)  d_in[2];
    const float* rain = (const float*)d_in[4];
    const float* W1   = (const float*)d_in[5];
    const float* b1   = (const float*)d_in[6];
    const float* W2   = (const float*)d_in[7];
    const float* b2   = (const float*)d_in[8];
    const float* Wa   = (const float*)d_in[9];
    const float* ba   = (const float*)d_in[10];

    const int R = in_sizes[0];      // B*N
    const int E = in_sizes[3];
    const int N = R / 2;

    float* out_h     = (float*)d_out;
    float* out_flows = out_h + R;

    char* wsB = (char*)d_ws;
    size_t off = 0;
    auto take = [&](size_t bytes) -> char* {
        char* p = wsB + off;
        off = (off + bytes + 255) & ~(size_t)255;
        return p;
    };
    float*    packed   = (float*)   take((size_t)4 * N * 4);
    float*    areas    = (float*)   take((size_t)R * 4);
    float*    netT     = (float*)   take((size_t)2 * N * 4);
    unsigned* counters = (unsigned*)take(MAXBUK * 4);

    const int nbuk = (N + 255) >> 8;
    int cap = (int)(((size_t)2 * E / (nbuk > 0 ? nbuk : 1)) * 5 / 4 + 512);
    cap = (cap + 255) & ~255;
    unsigned* keysG = (unsigned*)take((size_t)nbuk * cap * 4);
    float2*   valsG = (float2*)  take((size_t)nbuk * cap * 8);
    const bool binned = (off <= ws_size) && (nbuk <= 256);

    pack_kernel<<<(N + 255) / 256, 256, 0, stream>>>(h, rain, packed, netT,
                                                     counters, N);
    // 2R threads: 8-lane groups (8 k-eighths) per 4 rows
    node_kernel<<<(2 * R + 255) / 256, 256, 0, stream>>>(z, W1, b1, W2, b2,
                                                         Wa, ba, packed,
                                                         areas, N, R);
    if (binned) {
        edge_bin_kernel<<<(E + E1_EPB - 1) / E1_EPB, E1_TPB, 0, stream>>>(
            eidx, packed, out_flows, keysG, valsG, counters, E, nbuk, cap);
        bucket_reduce_kernel<<<nbuk, 512, 0, stream>>>(
            keysG, valsG, counters, h, rain, areas, out_h, N, cap);
    } else {
        edge_kernel<<<(E + 255) / 256, 256, 0, stream>>>(eidx, packed,
                                                         out_flows, netT, E);
        update_kernel<<<(N + 255) / 256, 256, 0, stream>>>(h, netT, areas,
                                                           out_h, N);
    }
}